// Round 10
// baseline (547.837 us; speedup 1.0000x reference)
//
#include <hip/hip_runtime.h>

// WaveGC wavelet conv. Round 10 = R9 + A-side LDS bypass:
// A fragments are loaded directly global->VGPR (16B/lane dwordx4, rows are
// wave-private so LDS staging of A was pure port traffic). LDS now holds only
// the B tile (16 KB): port traffic per k-step 160->96 KB vs 233 cyc MFMA,
// occupancy cap rises to ~6 blocks/CU (1088-block filter grid fully resident).
//
//  filter: F_t = A_t A_t^T (fp32 out) + fused row/col sumsq, triangular grid
//  st1   : PT  = NT(WgT_pad, x)
//  st4   : HT  = relu(NT(PT, G) + bg)    G = mask+scale staged from F fp32
//  st5   : combT = NT(HT, G) stored transposed
//  st6   : out = relu(NT(comb, WfT) + bf)
//
// ws (fused):   F fp32 [4][N][N] @0 (67.1M) | A4 @67.1M (67.1M) | tail @134.2M
// ws (fallback):F fp32 @0 | A1 @67.1M (16.8M) | tail @83.9M

#define NN 2048
#define NPW 4194304L   // N*N

typedef short bf16x8 __attribute__((ext_vector_type(8)));
typedef float f32x4  __attribute__((ext_vector_type(4)));

__device__ inline unsigned short bf16_rne(float f) {
    unsigned int u = __float_as_uint(f);
    u += 0x7fffu + ((u >> 16) & 1u);
    return (unsigned short)(u >> 16);
}
__device__ inline float bf16_f(unsigned short h) {
    return __uint_as_float((unsigned)h << 16);
}

__device__ inline void load_lds16(const void* g, void* l) {
    __builtin_amdgcn_global_load_lds(
        (const __attribute__((address_space(1))) unsigned int*)(unsigned long)g,
        (__attribute__((address_space(3))) unsigned int*)(unsigned long)l,
        16, 0, 0);
}

// masked+scaled+split 8-element chunk -> packed hi/lo uint4
__device__ inline void gmask_chunk(const float* src, float iv,
                                   uint4* hi, uint4* lo)
{
    float4 v0 = *(const float4*)src;
    float4 v1 = *(const float4*)(src + 4);
    float a[8] = {v0.x, v0.y, v0.z, v0.w, v1.x, v1.y, v1.z, v1.w};
    unsigned int hw[4], lw[4];
    #pragma unroll
    for (int d = 0; d < 4; ++d) {
        unsigned int hword = 0, lword = 0;
        #pragma unroll
        for (int e = 0; e < 2; ++e) {
            float g = a[d * 2 + e] * iv;
            g = (fabsf(g) > 1e-4f) ? g : 0.f;
            unsigned short h = bf16_rne(g);
            unsigned short l = bf16_rne(g - bf16_f(h));
            hword |= (unsigned int)h << (16 * e);
            lword |= (unsigned int)l << (16 * e);
        }
        hw[d] = hword; lw[d] = lword;
    }
    *hi = *(uint4*)hw; *lo = *(uint4*)lw;
}

// ---------------------------------------------------------------------------
// Filter: F = A A^T, fp32 out, fused row-sumsq; TRI: triangular grid with
// mirror writes + mirror col-sumsq. 128x64 block, BK=64, 4 waves.
// A fragments: direct global loads (wave-private rows). B tile: DMA into LDS.
// ---------------------------------------------------------------------------
template<bool TRI>
__global__ __launch_bounds__(256, 4)
void filter_tri(const unsigned short* __restrict__ Ah,
                const unsigned short* __restrict__ Al,
                float* __restrict__ F, float* __restrict__ sumsq, long sA)
{
    __shared__ unsigned short sBh[64 * 64];
    __shared__ unsigned short sBl[64 * 64];

    int z = blockIdx.z;
    Ah += z * sA; Al += z * sA;
    F  += z * NPW; sumsq += z * NN;
    const int K = NN, N = NN;

    int it, jt;
    if (TRI) {
        int rem = blockIdx.x, span = 32; it = 0;
        while (rem >= span) { rem -= span; ++it; span -= 2; }
        jt = 2 * it + rem;
    } else { it = blockIdx.y; jt = blockIdx.x; }
    int i0 = it * 128, j0 = jt * 64;

    int tid = threadIdx.x;
    int lane = tid & 63, w = tid >> 6;
    int wbase = w * 64;
    int wr = w * 32;
    int q = lane >> 4, r15 = lane & 15;

    // wave-private A rows for the two m-fragments
    long arow0 = (long)(i0 + wr + r15) * K;
    long arow1 = (long)(i0 + wr + 16 + r15) * K;

    f32x4 acc[2][4];
    #pragma unroll
    for (int i = 0; i < 2; ++i)
        #pragma unroll
        for (int j = 0; j < 4; ++j)
            acc[i][j] = (f32x4){0.f, 0.f, 0.f, 0.f};

    for (int k0 = 0; k0 < K; k0 += 64) {
        #pragma unroll
        for (int p = 0; p < 2; ++p) {
            int c = p * 256 + wbase + lane;
            int row = c >> 3;
            int gsw = (c & 7) ^ (row & 7);
            long off = (long)(j0 + row) * K + k0 + gsw * 8;
            int ldst = (p * 256 + wbase) * 8;
            load_lds16(Ah + off, &sBh[ldst]);   // B side == A array (A A^T)
            load_lds16(Al + off, &sBl[ldst]);
        }
        __syncthreads();

        #pragma unroll
        for (int s = 0; s < 2; ++s) {
            int g = s * 4 + q;
            long ka = k0 + g * 8;
            bf16x8 fAh[2], fAl[2], fBh[4], fBl[4];
            fAh[0] = *(const bf16x8*)(Ah + arow0 + ka);
            fAl[0] = *(const bf16x8*)(Al + arow0 + ka);
            fAh[1] = *(const bf16x8*)(Ah + arow1 + ka);
            fAl[1] = *(const bf16x8*)(Al + arow1 + ka);
            #pragma unroll
            for (int f = 0; f < 4; ++f) {
                int rb = f * 16 + r15;
                int ab = rb * 64 + ((g ^ (rb & 7)) * 8);
                fBh[f] = *(const bf16x8*)&sBh[ab];
                fBl[f] = *(const bf16x8*)&sBl[ab];
            }
            #pragma unroll
            for (int fi = 0; fi < 2; ++fi)
                #pragma unroll
                for (int fj = 0; fj < 4; ++fj) {
                    acc[fi][fj] = __builtin_amdgcn_mfma_f32_16x16x32_bf16(
                        fAh[fi], fBh[fj], acc[fi][fj], 0, 0, 0);
                    acc[fi][fj] = __builtin_amdgcn_mfma_f32_16x16x32_bf16(
                        fAh[fi], fBl[fj], acc[fi][fj], 0, 0, 0);
                    acc[fi][fj] = __builtin_amdgcn_mfma_f32_16x16x32_bf16(
                        fAl[fi], fBh[fj], acc[fi][fj], 0, 0, 0);
                }
        }
        __syncthreads();
    }

    // row-sumsq (direct contribution)
    #pragma unroll
    for (int fi = 0; fi < 2; ++fi)
        #pragma unroll
        for (int r = 0; r < 4; ++r) {
            float s = 0.f;
            #pragma unroll
            for (int fj = 0; fj < 4; ++fj) {
                float v = acc[fi][fj][r];
                s += v * v;
            }
            s += __shfl_xor(s, 1); s += __shfl_xor(s, 2);
            s += __shfl_xor(s, 4); s += __shfl_xor(s, 8);
            if (r15 == 0)
                atomicAdd(&sumsq[i0 + wr + fi * 16 + q * 4 + r], s);
        }

    bool mirror = TRI && (jt >= 2 * it + 2);
    if (mirror) {
        #pragma unroll
        for (int fj = 0; fj < 4; ++fj) {
            float s = 0.f;
            #pragma unroll
            for (int fi = 0; fi < 2; ++fi)
                #pragma unroll
                for (int r = 0; r < 4; ++r) {
                    float v = acc[fi][fj][r];
                    s += v * v;
                }
            s += __shfl_xor(s, 16); s += __shfl_xor(s, 32);
            if (lane < 16)
                atomicAdd(&sumsq[j0 + fj * 16 + lane], s);
        }
    }

    #pragma unroll
    for (int fi = 0; fi < 2; ++fi)
        #pragma unroll
        for (int fj = 0; fj < 4; ++fj) {
            int col = j0 + fj * 16 + r15;
            #pragma unroll
            for (int r = 0; r < 4; ++r) {
                int row = i0 + wr + fi * 16 + q * 4 + r;
                float v = acc[fi][fj][r];
                F[(long)row * N + col] = v;
                if (mirror) F[(long)col * N + row] = v;
            }
        }
}

// ---------------------------------------------------------------------------
// Generic NT GEMM. A side: direct global fragment loads (wave-private rows,
// clamped). B side: DMA into LDS, or GB: gmask-staged from fp32 F.
// BIASM: 0 none, 1 per-row, 2 per-col. TSTORE: write C transposed (st5).
// ---------------------------------------------------------------------------
template<int BIASM, bool RELU, bool OUTF32, bool GB, bool TSTORE>
__global__ __launch_bounds__(256, 4)
void nt_gemm(const unsigned short* __restrict__ Ah, const unsigned short* __restrict__ Al,
             const unsigned short* __restrict__ Bh, const unsigned short* __restrict__ Bl,
             const float* __restrict__ Bf,
             unsigned short* __restrict__ Ch, unsigned short* __restrict__ Cl,
             float* __restrict__ Cf,
             const float* __restrict__ bias, const float* __restrict__ rowss,
             int K, int a_rows, int b_rows, int i_valid, int j_valid, int ldc,
             long sA, long sB, long sC, int sBias)
{
    __shared__ unsigned short sBh[64 * 64];
    __shared__ unsigned short sBl[64 * 64];

    int z = blockIdx.z;
    Ah += z * sA; Al += z * sA;
    if (GB) Bf += z * sB; else { Bh += z * sB; Bl += z * sB; }
    if (OUTF32) Cf += z * sC; else { Ch += z * sC; Cl += z * sC; }
    if (BIASM)  bias += (long)z * sBias;
    if (GB) rowss += z * NN;

    int i0 = blockIdx.y * 128, j0 = blockIdx.x * 64;
    int tid = threadIdx.x;
    int lane = tid & 63, w = tid >> 6;
    int wbase = w * 64;
    int wr = w * 32;
    int q = lane >> 4, r15 = lane & 15;

    long arow0 = (long)min(i0 + wr + r15,      a_rows - 1) * K;
    long arow1 = (long)min(i0 + wr + 16 + r15, a_rows - 1) * K;

    f32x4 acc[2][4];
    #pragma unroll
    for (int i = 0; i < 2; ++i)
        #pragma unroll
        for (int j = 0; j < 4; ++j)
            acc[i][j] = (f32x4){0.f, 0.f, 0.f, 0.f};

    for (int k0 = 0; k0 < K; k0 += 64) {
        if (GB) {
            #pragma unroll
            for (int p = 0; p < 2; ++p) {
                int c = p * 256 + tid;
                int row = c >> 3, g = c & 7;
                int rb = min(j0 + row, b_rows - 1);
                float iv = 1.f / fmaxf(sqrtf(rowss[rb]), 1e-12f);
                uint4 hi, lo;
                gmask_chunk(Bf + (long)rb * K + k0 + g * 8, iv, &hi, &lo);
                int slot = row * 64 + ((g ^ (row & 7)) * 8);
                *(uint4*)&sBh[slot] = hi;
                *(uint4*)&sBl[slot] = lo;
            }
        } else {
            #pragma unroll
            for (int p = 0; p < 2; ++p) {
                int c = p * 256 + wbase + lane;
                int row = c >> 3;
                int gsw = (c & 7) ^ (row & 7);
                int rb = min(j0 + row, b_rows - 1);
                long off = (long)rb * K + k0 + gsw * 8;
                int ldst = (p * 256 + wbase) * 8;
                load_lds16(Bh + off, &sBh[ldst]);
                load_lds16(Bl + off, &sBl[ldst]);
            }
        }
        __syncthreads();

        #pragma unroll
        for (int s = 0; s < 2; ++s) {
            int g = s * 4 + q;
            long ka = k0 + g * 8;
            bf16x8 fAh[2], fAl[2], fBh[4], fBl[4];
            fAh[0] = *(const bf16x8*)(Ah + arow0 + ka);
            fAl[0] = *(const bf16x8*)(Al + arow0 + ka);
            fAh[1] = *(const bf16x8*)(Ah + arow1 + ka);
            fAl[1] = *(const bf16x8*)(Al + arow1 + ka);
            #pragma unroll
            for (int f = 0; f < 4; ++f) {
                int rb = f * 16 + r15;
                int ab = rb * 64 + ((g ^ (rb & 7)) * 8);
                fBh[f] = *(const bf16x8*)&sBh[ab];
                fBl[f] = *(const bf16x8*)&sBl[ab];
            }
            #pragma unroll
            for (int fi = 0; fi < 2; ++fi)
                #pragma unroll
                for (int fj = 0; fj < 4; ++fj) {
                    acc[fi][fj] = __builtin_amdgcn_mfma_f32_16x16x32_bf16(
                        fAh[fi], fBh[fj], acc[fi][fj], 0, 0, 0);
                    acc[fi][fj] = __builtin_amdgcn_mfma_f32_16x16x32_bf16(
                        fAh[fi], fBl[fj], acc[fi][fj], 0, 0, 0);
                    acc[fi][fj] = __builtin_amdgcn_mfma_f32_16x16x32_bf16(
                        fAl[fi], fBh[fj], acc[fi][fj], 0, 0, 0);
                }
        }
        __syncthreads();
    }

    #pragma unroll
    for (int fi = 0; fi < 2; ++fi)
        #pragma unroll
        for (int fj = 0; fj < 4; ++fj) {
            int col = j0 + fj * 16 + r15;
            if (col >= j_valid) continue;
            #pragma unroll
            for (int r = 0; r < 4; ++r) {
                int row = i0 + wr + fi * 16 + q * 4 + r;
                if (row >= i_valid) continue;
                float v = acc[fi][fj][r];
                if (BIASM == 1) v += bias[row];
                if (BIASM == 2) v += bias[col];
                if (RELU) v = fmaxf(v, 0.f);
                long off = TSTORE ? ((long)col * ldc + row)
                                  : ((long)row * ldc + col);
                if (OUTF32) {
                    Cf[off] = v;
                } else {
                    unsigned short h = bf16_rne(v);
                    Ch[off] = h;
                    Cl[off] = bf16_rne(v - bf16_f(h));
                }
            }
        }
}

// ---------------------------------------------------------------------------
// Prep: A_t[i][k] = V[i][k]*sqrt(s_t[k]) -> bf16 hi/lo, all 4 t per thread
// (one evc read). Plane t at Ah + t*2*NPW (hi) / + NPW (lo).
// Zeroes sumsq (8192 floats) on blockIdx.x<32.
// ---------------------------------------------------------------------------
__global__ __launch_bounds__(256)
void prep_filter_A(const float* __restrict__ V, const float* __restrict__ sig,
                   unsigned short* __restrict__ Ah, float* __restrict__ zs)
{
    if (zs && blockIdx.x < 32)
        zs[blockIdx.x * 256 + threadIdx.x] = 0.f;
    long idx = ((long)blockIdx.x * 256 + threadIdx.x) * 4;
    int k = (int)(idx & (NN - 1));
    float4 v = *(const float4*)(V + idx);
    float vv[4] = {v.x, v.y, v.z, v.w};
    float4 srow[4];
    #pragma unroll
    for (int i = 0; i < 4; ++i)
        srow[i] = *(const float4*)(sig + (k + i) * 4);
    #pragma unroll
    for (int t = 0; t < 4; ++t) {
        float sq[4] = {((const float*)&srow[0])[t], ((const float*)&srow[1])[t],
                       ((const float*)&srow[2])[t], ((const float*)&srow[3])[t]};
        ushort4 hi, lo;
        unsigned short h;
        float a;
        a = vv[0] * sqrtf(sq[0]); h = bf16_rne(a); hi.x = h; lo.x = bf16_rne(a - bf16_f(h));
        a = vv[1] * sqrtf(sq[1]); h = bf16_rne(a); hi.y = h; lo.y = bf16_rne(a - bf16_f(h));
        a = vv[2] * sqrtf(sq[2]); h = bf16_rne(a); hi.z = h; lo.z = bf16_rne(a - bf16_f(h));
        a = vv[3] * sqrtf(sq[3]); h = bf16_rne(a); hi.w = h; lo.w = bf16_rne(a - bf16_f(h));
        *(ushort4*)(Ah + (long)t * 2 * NPW + idx) = hi;
        *(ushort4*)(Ah + (long)t * 2 * NPW + NPW + idx) = lo;
    }
}

// Fallback prep: single t.
__global__ __launch_bounds__(256)
void prep_filter_A1(const float* __restrict__ V, const float* __restrict__ sig, int t,
                    unsigned short* __restrict__ Ah, unsigned short* __restrict__ Al,
                    float* __restrict__ zs)
{
    if (zs && blockIdx.x < 32)
        zs[blockIdx.x * 256 + threadIdx.x] = 0.f;
    long idx = ((long)blockIdx.x * 256 + threadIdx.x) * 4;
    int k = (int)(idx & (NN - 1));
    float4 v = *(const float4*)(V + idx);
    float a[4];
    a[0] = v.x * sqrtf(sig[(k + 0) * 4 + t]);
    a[1] = v.y * sqrtf(sig[(k + 1) * 4 + t]);
    a[2] = v.z * sqrtf(sig[(k + 2) * 4 + t]);
    a[3] = v.w * sqrtf(sig[(k + 3) * 4 + t]);
    ushort4 hi, lo;
    unsigned short h;
    h = bf16_rne(a[0]); hi.x = h; lo.x = bf16_rne(a[0] - bf16_f(h));
    h = bf16_rne(a[1]); hi.y = h; lo.y = bf16_rne(a[1] - bf16_f(h));
    h = bf16_rne(a[2]); hi.z = h; lo.z = bf16_rne(a[2] - bf16_f(h));
    h = bf16_rne(a[3]); hi.w = h; lo.w = bf16_rne(a[3] - bf16_f(h));
    *(ushort4*)(Ah + idx) = hi;
    *(ushort4*)(Al + idx) = lo;
}

__global__ __launch_bounds__(256)
void split_kernel(const float* __restrict__ src,
                  unsigned short* __restrict__ oh, unsigned short* __restrict__ ol,
                  const float* __restrict__ bg, float* __restrict__ bgp)
{
    if (blockIdx.x == 0 && bgp) {
        #pragma unroll
        for (int p = 0; p < 4; ++p) {
            int i = p * 256 + threadIdx.x;
            int t = i >> 8, n = i & 255;
            bgp[i] = (n < 192) ? bg[t * 192 + n] : 0.f;
        }
    }
    long idx = ((long)blockIdx.x * 256 + threadIdx.x) * 4;
    float4 v = *(const float4*)(src + idx);
    float a[4] = {v.x, v.y, v.z, v.w};
    ushort4 hi, lo;
    unsigned short h;
    h = bf16_rne(a[0]); hi.x = h; lo.x = bf16_rne(a[0] - bf16_f(h));
    h = bf16_rne(a[1]); hi.y = h; lo.y = bf16_rne(a[1] - bf16_f(h));
    h = bf16_rne(a[2]); hi.z = h; lo.z = bf16_rne(a[2] - bf16_f(h));
    h = bf16_rne(a[3]); hi.w = h; lo.w = bf16_rne(a[3] - bf16_f(h));
    *(ushort4*)(oh + idx) = hi;
    *(ushort4*)(ol + idx) = lo;
}

__global__ __launch_bounds__(256)
void transpose_split(const float* __restrict__ src, int src_ld, int n_rows, int n_valid,
                     int kcols, unsigned short* __restrict__ oh, unsigned short* __restrict__ ol,
                     long sbs, long sbd)
{
    long idx = (long)blockIdx.x * 256 + threadIdx.x;
    if (idx >= (long)n_rows * kcols) return;
    int n = (int)(idx / kcols), k = (int)(idx % kcols);
    float v = (n < n_valid) ? src[(long)blockIdx.y * sbs + (long)k * src_ld + n] : 0.f;
    unsigned short h = bf16_rne(v);
    long o = (long)blockIdx.y * sbd + idx;
    oh[o] = h;
    ol[o] = bf16_rne(v - bf16_f(h));
}

// ---------------------------------------------------------------------------
extern "C" void kernel_launch(void* const* d_in, const int* in_sizes, int n_in,
                              void* d_out, int out_size, void* d_ws, size_t ws_size,
                              hipStream_t stream)
{
    const float* x   = (const float*)d_in[0];
    const float* evc = (const float*)d_in[1];
    const float* sig = (const float*)d_in[2];
    const float* Wg  = (const float*)d_in[3];
    const float* bg  = (const float*)d_in[4];
    const float* Wf  = (const float*)d_in[5];
    const float* bf  = (const float*)d_in[6];
    float* out = (float*)d_out;

    char* w = (char*)d_ws;
    float* F = (float*)w;                                       // [4][N][N] fp32
    char* R = w + 67108864L;
    unsigned short* A1 = (unsigned short*)R;                    // fallback pair
    unsigned short* xh   = (unsigned short*)R;
    unsigned short* xl   = xh + (long)NN * 768;
    unsigned short* WgTh = (unsigned short*)(R + 6291456L);
    unsigned short* WgTl = WgTh + 4L * 256 * 768;
    unsigned short* PTh  = (unsigned short*)(R + 9437184L);
    unsigned short* PTl  = PTh + 4L * 192 * NN;
    unsigned short* HTh  = (unsigned short*)R;
    unsigned short* HTl  = HTh + 4L * 192 * NN;
    unsigned short* combh = (unsigned short*)(R + 9437184L);
    unsigned short* combl = combh + (long)NN * 768;
    unsigned short* WfTh = (unsigned short*)w;                  // overlays dead F
    unsigned short* WfTl = WfTh + 768L * 768;

    const bool fused = ws_size >= 134254592UL;
    float* rowss = (float*)(fused ? (w + 134217728L) : (w + 83886080L));
    float* bgp   = rowss + 4 * NN;

    if (fused) {
        unsigned short* A4 = (unsigned short*)R;   // [4][hi|lo][N*N]
        prep_filter_A<<<4096, 256, 0, stream>>>(evc, sig, A4, rowss);
        filter_tri<true><<<dim3(272, 1, 4), 256, 0, stream>>>(
            A4, A4 + NPW, F, rowss, 2 * NPW);
    } else {
        for (int t = 0; t < 4; ++t) {
            prep_filter_A1<<<4096, 256, 0, stream>>>(
                evc, sig, t, A1, A1 + NPW, t == 0 ? rowss : nullptr);
            filter_tri<false><<<dim3(32, 16, 1), 256, 0, stream>>>(
                A1, A1 + NPW, F + t * NPW, rowss + t * NN, 0L);
        }
    }

    split_kernel<<<1536, 256, 0, stream>>>(x, xh, xl, bg, bgp);
    transpose_split<<<dim3(768, 4), 256, 0, stream>>>(
        Wg, 192, 256, 192, 768, WgTh, WgTl, 768L * 192, 256L * 768);

    // st1: PT[t] = NT(WgT_pad[t], x), K=768
    nt_gemm<0, false, false, false, false><<<dim3(32, 2, 4), 256, 0, stream>>>(
        WgTh, WgTl, xh, xl, nullptr, PTh, PTl, nullptr, nullptr, nullptr,
        768, 256, NN, 192, NN, NN, 256L * 768, 0L, 192L * NN, 0);

    // st4: HT[t] = relu(NT(PT[t], G[t]) + bg[t]); G staged from F fp32 (B side)
    nt_gemm<1, true, false, true, false><<<dim3(32, 2, 4), 256, 0, stream>>>(
        PTh, PTl, nullptr, nullptr, F, HTh, HTl, nullptr, bgp, rowss,
        NN, 192, NN, 192, NN, NN, 192L * NN, NPW, 192L * NN, 256);

    // st5 (swapped): combT-tiles = NT(HT, G), stored transposed.
    nt_gemm<0, false, false, true, true><<<dim3(32, 2, 4), 256, 0, stream>>>(
        HTh, HTl, nullptr, nullptr, F, combh, combl, nullptr, nullptr, rowss,
        NN, 192, NN, 192, NN, 768, 192L * NN, NPW, 192L, 0);

    // st6: out = relu(NT(comb, WfT) + bf)
    transpose_split<<<dim3(2304, 1), 256, 0, stream>>>(
        Wf, 768, 768, 768, 768, WfTh, WfTl, 0L, 0L);
    nt_gemm<2, true, true, false, false><<<dim3(12, 16, 1), 256, 0, stream>>>(
        combh, combl, WfTh, WfTl, nullptr, nullptr, nullptr, out, bf, nullptr,
        768, NN, 768, NN, 768, 768, 0L, 0L, 0L, 0);
}

// Round 11
// 409.505 us; speedup vs baseline: 1.3378x; 1.3378x over previous
//
#include <hip/hip_runtime.h>

// WaveGC wavelet conv. Round 11 = R9 (best, 420 µs) + persistent work-stealing
// filter. R10 post-mortem: direct global A-fragment loads are 16-row gathers
// (lane stride K*2B) -> latency-bound, MfmaUtil collapsed; reverted to DMA
// staging. R9's filter ran 1088 blocks at 3/CU = 768 capacity -> 1.42 passes,
// the 320-block tail pass idles ~58% of the machine. Persistent grid of 768
// blocks + atomic tile counter gives uniform residency; diagonal tiles skip
// B staging (B rows are inside the A tile).
//
//  filter: F_t = A_t A_t^T (fp32) + fused row/col sumsq, triangular tiles
//  st1   : PT  = NT(WgT_pad, x)
//  st4   : HT  = relu(NT(PT, G) + bg)    G = mask+scale staged from F fp32
//  st5   : combT = NT(HT, G) stored transposed
//  st6   : out = relu(NT(comb, WfT) + bf)
//
// ws (fused):   F fp32 [4][N][N] @0 (67.1M) | A4 @67.1M (67.1M) | tail @134.2M
// ws (fallback):F fp32 @0 | A1 @67.1M (16.8M) | tail @83.9M
// tile counter lives in the bgp slot (only used after the filter phase).

#define NN 2048
#define NPW 4194304L   // N*N

typedef short bf16x8 __attribute__((ext_vector_type(8)));
typedef float f32x4  __attribute__((ext_vector_type(4)));

__device__ inline unsigned short bf16_rne(float f) {
    unsigned int u = __float_as_uint(f);
    u += 0x7fffu + ((u >> 16) & 1u);
    return (unsigned short)(u >> 16);
}
__device__ inline float bf16_f(unsigned short h) {
    return __uint_as_float((unsigned)h << 16);
}

__device__ inline void load_lds16(const void* g, void* l) {
    __builtin_amdgcn_global_load_lds(
        (const __attribute__((address_space(1))) unsigned int*)(unsigned long)g,
        (__attribute__((address_space(3))) unsigned int*)(unsigned long)l,
        16, 0, 0);
}

// masked+scaled+split 8-element chunk -> packed hi/lo uint4
__device__ inline void gmask_chunk(const float* src, float iv,
                                   uint4* hi, uint4* lo)
{
    float4 v0 = *(const float4*)src;
    float4 v1 = *(const float4*)(src + 4);
    float a[8] = {v0.x, v0.y, v0.z, v0.w, v1.x, v1.y, v1.z, v1.w};
    unsigned int hw[4], lw[4];
    #pragma unroll
    for (int d = 0; d < 4; ++d) {
        unsigned int hword = 0, lword = 0;
        #pragma unroll
        for (int e = 0; e < 2; ++e) {
            float g = a[d * 2 + e] * iv;
            g = (fabsf(g) > 1e-4f) ? g : 0.f;
            unsigned short h = bf16_rne(g);
            unsigned short l = bf16_rne(g - bf16_f(h));
            hword |= (unsigned int)h << (16 * e);
            lword |= (unsigned int)l << (16 * e);
        }
        hw[d] = hword; lw[d] = lword;
    }
    *hi = *(uint4*)hw; *lo = *(uint4*)lw;
}

// ---------------------------------------------------------------------------
// Persistent triangular filter: F = A A^T fp32 + fused row/col sumsq.
// 128x64 tile, BK=64, 4 waves, DMA staging (R9-proven). Tiles distributed by
// atomic counter; t = idx/272, triangular pair = idx%272. Diagonal tiles
// ((jt>>1)==it) read B fragments from the A tile (no B staging).
// ---------------------------------------------------------------------------
__global__ __launch_bounds__(256, 3)
void filter_persist(const unsigned short* __restrict__ AhB,
                    const unsigned short* __restrict__ AlB,
                    float* __restrict__ FB, float* __restrict__ ssB,
                    long sA, int ntiles, unsigned* __restrict__ ctr)
{
    __shared__ unsigned short sAh[128 * 64];
    __shared__ unsigned short sAl[128 * 64];
    __shared__ unsigned short sBh[64 * 64];
    __shared__ unsigned short sBl[64 * 64];
    __shared__ int s_idx;

    const int K = NN, N = NN;
    int tid = threadIdx.x;
    int lane = tid & 63, w = tid >> 6;
    int wbase = w * 64;
    int wr = w * 32;
    int q = lane >> 4, r15 = lane & 15;

    for (;;) {
        if (tid == 0) s_idx = (int)atomicAdd(ctr, 1u);
        __syncthreads();
        int idx = s_idx;
        if (idx >= ntiles) return;

        int z = idx / 272;
        int rem = idx - z * 272;
        int it = 0, span = 32;
        while (rem >= span) { rem -= span; ++it; span -= 2; }
        int jt = 2 * it + rem;
        int i0 = it * 128, j0 = jt * 64;
        bool diag = (jt >> 1) == it;
        int boff = (jt & 1) * 64;

        const unsigned short* Ah = AhB + z * sA;
        const unsigned short* Al = AlB + z * sA;
        float* F = FB + (long)z * NPW;
        float* sumsq = ssB + z * NN;

        f32x4 acc[2][4];
        #pragma unroll
        for (int i = 0; i < 2; ++i)
            #pragma unroll
            for (int j = 0; j < 4; ++j)
                acc[i][j] = (f32x4){0.f, 0.f, 0.f, 0.f};

        for (int k0 = 0; k0 < K; k0 += 64) {
            #pragma unroll
            for (int p = 0; p < 4; ++p) {
                int c = p * 256 + wbase + lane;
                int row = c >> 3;
                int gsw = (c & 7) ^ (row & 7);
                long off = (long)(i0 + row) * K + k0 + gsw * 8;
                int ldst = (p * 256 + wbase) * 8;
                load_lds16(Ah + off, &sAh[ldst]);
                load_lds16(Al + off, &sAl[ldst]);
            }
            if (!diag) {
                #pragma unroll
                for (int p = 0; p < 2; ++p) {
                    int c = p * 256 + wbase + lane;
                    int row = c >> 3;
                    int gsw = (c & 7) ^ (row & 7);
                    long off = (long)(j0 + row) * K + k0 + gsw * 8;
                    int ldst = (p * 256 + wbase) * 8;
                    load_lds16(Ah + off, &sBh[ldst]);
                    load_lds16(Al + off, &sBl[ldst]);
                }
            }
            __syncthreads();

            const unsigned short* bh = diag ? sAh : sBh;
            const unsigned short* bl = diag ? sAl : sBl;
            int broff = diag ? boff : 0;

            #pragma unroll
            for (int s = 0; s < 2; ++s) {
                int g = s * 4 + q;
                bf16x8 fAh[2], fAl[2], fBh[4], fBl[4];
                #pragma unroll
                for (int f = 0; f < 2; ++f) {
                    int ra = wr + f * 16 + r15;
                    int aa = ra * 64 + ((g ^ (ra & 7)) * 8);
                    fAh[f] = *(const bf16x8*)&sAh[aa];
                    fAl[f] = *(const bf16x8*)&sAl[aa];
                }
                #pragma unroll
                for (int f = 0; f < 4; ++f) {
                    int rb = broff + f * 16 + r15;
                    int ab = rb * 64 + ((g ^ (rb & 7)) * 8);
                    fBh[f] = *(const bf16x8*)&bh[ab];
                    fBl[f] = *(const bf16x8*)&bl[ab];
                }
                #pragma unroll
                for (int fi = 0; fi < 2; ++fi)
                    #pragma unroll
                    for (int fj = 0; fj < 4; ++fj) {
                        acc[fi][fj] = __builtin_amdgcn_mfma_f32_16x16x32_bf16(
                            fAh[fi], fBh[fj], acc[fi][fj], 0, 0, 0);
                        acc[fi][fj] = __builtin_amdgcn_mfma_f32_16x16x32_bf16(
                            fAh[fi], fBl[fj], acc[fi][fj], 0, 0, 0);
                        acc[fi][fj] = __builtin_amdgcn_mfma_f32_16x16x32_bf16(
                            fAl[fi], fBh[fj], acc[fi][fj], 0, 0, 0);
                    }
            }
            __syncthreads();
        }

        // row-sumsq (direct contribution)
        #pragma unroll
        for (int fi = 0; fi < 2; ++fi)
            #pragma unroll
            for (int r = 0; r < 4; ++r) {
                float s = 0.f;
                #pragma unroll
                for (int fj = 0; fj < 4; ++fj) {
                    float v = acc[fi][fj][r];
                    s += v * v;
                }
                s += __shfl_xor(s, 1); s += __shfl_xor(s, 2);
                s += __shfl_xor(s, 4); s += __shfl_xor(s, 8);
                if (r15 == 0)
                    atomicAdd(&sumsq[i0 + wr + fi * 16 + q * 4 + r], s);
            }

        bool mirror = (jt >= 2 * it + 2);
        if (mirror) {
            #pragma unroll
            for (int fj = 0; fj < 4; ++fj) {
                float s = 0.f;
                #pragma unroll
                for (int fi = 0; fi < 2; ++fi)
                    #pragma unroll
                    for (int r = 0; r < 4; ++r) {
                        float v = acc[fi][fj][r];
                        s += v * v;
                    }
                s += __shfl_xor(s, 16); s += __shfl_xor(s, 32);
                if (lane < 16)
                    atomicAdd(&sumsq[j0 + fj * 16 + lane], s);
            }
        }

        #pragma unroll
        for (int fi = 0; fi < 2; ++fi)
            #pragma unroll
            for (int fj = 0; fj < 4; ++fj) {
                int col = j0 + fj * 16 + r15;
                #pragma unroll
                for (int r = 0; r < 4; ++r) {
                    int row = i0 + wr + fi * 16 + q * 4 + r;
                    float v = acc[fi][fj][r];
                    F[(long)row * N + col] = v;
                    if (mirror) F[(long)col * N + row] = v;
                }
            }
    }
}

// ---------------------------------------------------------------------------
// Generic NT GEMM (R9 body). A side: DMA staged. B side: DMA, or GB:
// gmask-staged from fp32 F. BIASM: 0 none, 1 per-row, 2 per-col.
// TSTORE: write C transposed (st5).
// ---------------------------------------------------------------------------
template<int BIASM, bool RELU, bool OUTF32, bool GB, bool TSTORE>
__global__ __launch_bounds__(256, 3)
void nt_gemm(const unsigned short* __restrict__ Ah, const unsigned short* __restrict__ Al,
             const unsigned short* __restrict__ Bh, const unsigned short* __restrict__ Bl,
             const float* __restrict__ Bf,
             unsigned short* __restrict__ Ch, unsigned short* __restrict__ Cl,
             float* __restrict__ Cf,
             const float* __restrict__ bias, const float* __restrict__ rowss,
             int K, int a_rows, int b_rows, int i_valid, int j_valid, int ldc,
             long sA, long sB, long sC, int sBias)
{
    __shared__ unsigned short sAh[128 * 64];
    __shared__ unsigned short sAl[128 * 64];
    __shared__ unsigned short sBh[64 * 64];
    __shared__ unsigned short sBl[64 * 64];

    int z = blockIdx.z;
    Ah += z * sA; Al += z * sA;
    if (GB) Bf += z * sB; else { Bh += z * sB; Bl += z * sB; }
    if (OUTF32) Cf += z * sC; else { Ch += z * sC; Cl += z * sC; }
    if (BIASM)  bias += (long)z * sBias;
    if (GB) rowss += z * NN;

    int i0 = blockIdx.y * 128, j0 = blockIdx.x * 64;
    int tid = threadIdx.x;
    int lane = tid & 63, w = tid >> 6;
    int wbase = w * 64;
    int wr = w * 32;
    int q = lane >> 4, r15 = lane & 15;

    f32x4 acc[2][4];
    #pragma unroll
    for (int i = 0; i < 2; ++i)
        #pragma unroll
        for (int j = 0; j < 4; ++j)
            acc[i][j] = (f32x4){0.f, 0.f, 0.f, 0.f};

    for (int k0 = 0; k0 < K; k0 += 64) {
        #pragma unroll
        for (int p = 0; p < 4; ++p) {
            int c = p * 256 + wbase + lane;
            int row = c >> 3;
            int gsw = (c & 7) ^ (row & 7);
            int ra = min(i0 + row, a_rows - 1);
            long off = (long)ra * K + k0 + gsw * 8;
            int ldst = (p * 256 + wbase) * 8;
            load_lds16(Ah + off, &sAh[ldst]);
            load_lds16(Al + off, &sAl[ldst]);
        }
        if (GB) {
            #pragma unroll
            for (int p = 0; p < 2; ++p) {
                int c = p * 256 + tid;
                int row = c >> 3, g = c & 7;
                int rb = min(j0 + row, b_rows - 1);
                float iv = 1.f / fmaxf(sqrtf(rowss[rb]), 1e-12f);
                uint4 hi, lo;
                gmask_chunk(Bf + (long)rb * K + k0 + g * 8, iv, &hi, &lo);
                int slot = row * 64 + ((g ^ (row & 7)) * 8);
                *(uint4*)&sBh[slot] = hi;
                *(uint4*)&sBl[slot] = lo;
            }
        } else {
            #pragma unroll
            for (int p = 0; p < 2; ++p) {
                int c = p * 256 + wbase + lane;
                int row = c >> 3;
                int gsw = (c & 7) ^ (row & 7);
                int rb = min(j0 + row, b_rows - 1);
                long off = (long)rb * K + k0 + gsw * 8;
                int ldst = (p * 256 + wbase) * 8;
                load_lds16(Bh + off, &sBh[ldst]);
                load_lds16(Bl + off, &sBl[ldst]);
            }
        }
        __syncthreads();

        #pragma unroll
        for (int s = 0; s < 2; ++s) {
            int g = s * 4 + q;
            bf16x8 fAh[2], fAl[2], fBh[4], fBl[4];
            #pragma unroll
            for (int f = 0; f < 2; ++f) {
                int ra = wr + f * 16 + r15;
                int aa = ra * 64 + ((g ^ (ra & 7)) * 8);
                fAh[f] = *(const bf16x8*)&sAh[aa];
                fAl[f] = *(const bf16x8*)&sAl[aa];
            }
            #pragma unroll
            for (int f = 0; f < 4; ++f) {
                int rb = f * 16 + r15;
                int ab = rb * 64 + ((g ^ (rb & 7)) * 8);
                fBh[f] = *(const bf16x8*)&sBh[ab];
                fBl[f] = *(const bf16x8*)&sBl[ab];
            }
            #pragma unroll
            for (int fi = 0; fi < 2; ++fi)
                #pragma unroll
                for (int fj = 0; fj < 4; ++fj) {
                    acc[fi][fj] = __builtin_amdgcn_mfma_f32_16x16x32_bf16(
                        fAh[fi], fBh[fj], acc[fi][fj], 0, 0, 0);
                    acc[fi][fj] = __builtin_amdgcn_mfma_f32_16x16x32_bf16(
                        fAh[fi], fBl[fj], acc[fi][fj], 0, 0, 0);
                    acc[fi][fj] = __builtin_amdgcn_mfma_f32_16x16x32_bf16(
                        fAl[fi], fBh[fj], acc[fi][fj], 0, 0, 0);
                }
        }
        __syncthreads();
    }

    #pragma unroll
    for (int fi = 0; fi < 2; ++fi)
        #pragma unroll
        for (int fj = 0; fj < 4; ++fj) {
            int col = j0 + fj * 16 + r15;
            if (col >= j_valid) continue;
            #pragma unroll
            for (int r = 0; r < 4; ++r) {
                int row = i0 + wr + fi * 16 + q * 4 + r;
                if (row >= i_valid) continue;
                float v = acc[fi][fj][r];
                if (BIASM == 1) v += bias[row];
                if (BIASM == 2) v += bias[col];
                if (RELU) v = fmaxf(v, 0.f);
                long off = TSTORE ? ((long)col * ldc + row)
                                  : ((long)row * ldc + col);
                if (OUTF32) {
                    Cf[off] = v;
                } else {
                    unsigned short h = bf16_rne(v);
                    Ch[off] = h;
                    Cl[off] = bf16_rne(v - bf16_f(h));
                }
            }
        }
}

// ---------------------------------------------------------------------------
// Prep (fused): all 4 t per thread (one evc read); zeroes sumsq + counter.
// ---------------------------------------------------------------------------
__global__ __launch_bounds__(256)
void prep_filter_A(const float* __restrict__ V, const float* __restrict__ sig,
                   unsigned short* __restrict__ Ah, float* __restrict__ zs,
                   unsigned* __restrict__ ctr)
{
    if (blockIdx.x < 32)
        zs[blockIdx.x * 256 + threadIdx.x] = 0.f;
    if (blockIdx.x == 32 && threadIdx.x == 0)
        *ctr = 0u;
    long idx = ((long)blockIdx.x * 256 + threadIdx.x) * 4;
    int k = (int)(idx & (NN - 1));
    float4 v = *(const float4*)(V + idx);
    float vv[4] = {v.x, v.y, v.z, v.w};
    float4 srow[4];
    #pragma unroll
    for (int i = 0; i < 4; ++i)
        srow[i] = *(const float4*)(sig + (k + i) * 4);
    #pragma unroll
    for (int t = 0; t < 4; ++t) {
        float sq[4] = {((const float*)&srow[0])[t], ((const float*)&srow[1])[t],
                       ((const float*)&srow[2])[t], ((const float*)&srow[3])[t]};
        ushort4 hi, lo;
        unsigned short h;
        float a;
        a = vv[0] * sqrtf(sq[0]); h = bf16_rne(a); hi.x = h; lo.x = bf16_rne(a - bf16_f(h));
        a = vv[1] * sqrtf(sq[1]); h = bf16_rne(a); hi.y = h; lo.y = bf16_rne(a - bf16_f(h));
        a = vv[2] * sqrtf(sq[2]); h = bf16_rne(a); hi.z = h; lo.z = bf16_rne(a - bf16_f(h));
        a = vv[3] * sqrtf(sq[3]); h = bf16_rne(a); hi.w = h; lo.w = bf16_rne(a - bf16_f(h));
        *(ushort4*)(Ah + (long)t * 2 * NPW + idx) = hi;
        *(ushort4*)(Ah + (long)t * 2 * NPW + NPW + idx) = lo;
    }
}

// Fallback prep: single t; zeroes counter every launch, sumsq only when zs set.
__global__ __launch_bounds__(256)
void prep_filter_A1(const float* __restrict__ V, const float* __restrict__ sig, int t,
                    unsigned short* __restrict__ Ah, unsigned short* __restrict__ Al,
                    float* __restrict__ zs, unsigned* __restrict__ ctr)
{
    if (zs && blockIdx.x < 32)
        zs[blockIdx.x * 256 + threadIdx.x] = 0.f;
    if (blockIdx.x == 32 && threadIdx.x == 0)
        *ctr = 0u;
    long idx = ((long)blockIdx.x * 256 + threadIdx.x) * 4;
    int k = (int)(idx & (NN - 1));
    float4 v = *(const float4*)(V + idx);
    float a[4];
    a[0] = v.x * sqrtf(sig[(k + 0) * 4 + t]);
    a[1] = v.y * sqrtf(sig[(k + 1) * 4 + t]);
    a[2] = v.z * sqrtf(sig[(k + 2) * 4 + t]);
    a[3] = v.w * sqrtf(sig[(k + 3) * 4 + t]);
    ushort4 hi, lo;
    unsigned short h;
    h = bf16_rne(a[0]); hi.x = h; lo.x = bf16_rne(a[0] - bf16_f(h));
    h = bf16_rne(a[1]); hi.y = h; lo.y = bf16_rne(a[1] - bf16_f(h));
    h = bf16_rne(a[2]); hi.z = h; lo.z = bf16_rne(a[2] - bf16_f(h));
    h = bf16_rne(a[3]); hi.w = h; lo.w = bf16_rne(a[3] - bf16_f(h));
    *(ushort4*)(Ah + idx) = hi;
    *(ushort4*)(Al + idx) = lo;
}

__global__ __launch_bounds__(256)
void split_kernel(const float* __restrict__ src,
                  unsigned short* __restrict__ oh, unsigned short* __restrict__ ol,
                  const float* __restrict__ bg, float* __restrict__ bgp)
{
    if (blockIdx.x == 0 && bgp) {
        #pragma unroll
        for (int p = 0; p < 4; ++p) {
            int i = p * 256 + threadIdx.x;
            int t = i >> 8, n = i & 255;
            bgp[i] = (n < 192) ? bg[t * 192 + n] : 0.f;
        }
    }
    long idx = ((long)blockIdx.x * 256 + threadIdx.x) * 4;
    float4 v = *(const float4*)(src + idx);
    float a[4] = {v.x, v.y, v.z, v.w};
    ushort4 hi, lo;
    unsigned short h;
    h = bf16_rne(a[0]); hi.x = h; lo.x = bf16_rne(a[0] - bf16_f(h));
    h = bf16_rne(a[1]); hi.y = h; lo.y = bf16_rne(a[1] - bf16_f(h));
    h = bf16_rne(a[2]); hi.z = h; lo.z = bf16_rne(a[2] - bf16_f(h));
    h = bf16_rne(a[3]); hi.w = h; lo.w = bf16_rne(a[3] - bf16_f(h));
    *(ushort4*)(oh + idx) = hi;
    *(ushort4*)(ol + idx) = lo;
}

__global__ __launch_bounds__(256)
void transpose_split(const float* __restrict__ src, int src_ld, int n_rows, int n_valid,
                     int kcols, unsigned short* __restrict__ oh, unsigned short* __restrict__ ol,
                     long sbs, long sbd)
{
    long idx = (long)blockIdx.x * 256 + threadIdx.x;
    if (idx >= (long)n_rows * kcols) return;
    int n = (int)(idx / kcols), k = (int)(idx % kcols);
    float v = (n < n_valid) ? src[(long)blockIdx.y * sbs + (long)k * src_ld + n] : 0.f;
    unsigned short h = bf16_rne(v);
    long o = (long)blockIdx.y * sbd + idx;
    oh[o] = h;
    ol[o] = bf16_rne(v - bf16_f(h));
}

// ---------------------------------------------------------------------------
extern "C" void kernel_launch(void* const* d_in, const int* in_sizes, int n_in,
                              void* d_out, int out_size, void* d_ws, size_t ws_size,
                              hipStream_t stream)
{
    const float* x   = (const float*)d_in[0];
    const float* evc = (const float*)d_in[1];
    const float* sig = (const float*)d_in[2];
    const float* Wg  = (const float*)d_in[3];
    const float* bg  = (const float*)d_in[4];
    const float* Wf  = (const float*)d_in[5];
    const float* bf  = (const float*)d_in[6];
    float* out = (float*)d_out;

    char* w = (char*)d_ws;
    float* F = (float*)w;                                       // [4][N][N] fp32
    char* R = w + 67108864L;
    unsigned short* A1 = (unsigned short*)R;                    // fallback pair
    unsigned short* xh   = (unsigned short*)R;
    unsigned short* xl   = xh + (long)NN * 768;
    unsigned short* WgTh = (unsigned short*)(R + 6291456L);
    unsigned short* WgTl = WgTh + 4L * 256 * 768;
    unsigned short* PTh  = (unsigned short*)(R + 9437184L);
    unsigned short* PTl  = PTh + 4L * 192 * NN;
    unsigned short* HTh  = (unsigned short*)R;
    unsigned short* HTl  = HTh + 4L * 192 * NN;
    unsigned short* combh = (unsigned short*)(R + 9437184L);
    unsigned short* combl = combh + (long)NN * 768;
    unsigned short* WfTh = (unsigned short*)w;                  // overlays dead F
    unsigned short* WfTl = WfTh + 768L * 768;

    const bool fused = ws_size >= 134254592UL;
    float* rowss = (float*)(fused ? (w + 134217728L) : (w + 83886080L));
    float* bgp   = rowss + 4 * NN;
    unsigned* ctr = (unsigned*)bgp;   // bgp slot is dead until split_kernel

    if (fused) {
        unsigned short* A4 = (unsigned short*)R;   // [4][hi|lo][N*N]
        prep_filter_A<<<4096, 256, 0, stream>>>(evc, sig, A4, rowss, ctr);
        filter_persist<<<768, 256, 0, stream>>>(
            A4, A4 + NPW, F, rowss, 2 * NPW, 1088, ctr);
    } else {
        for (int t = 0; t < 4; ++t) {
            prep_filter_A1<<<4096, 256, 0, stream>>>(
                evc, sig, t, A1, A1 + NPW, t == 0 ? rowss : nullptr, ctr);
            filter_persist<<<272, 256, 0, stream>>>(
                A1, A1 + NPW, F + t * NPW, rowss + t * NN, 0L, 272, ctr);
        }
    }

    split_kernel<<<1536, 256, 0, stream>>>(x, xh, xl, bg, bgp);
    transpose_split<<<dim3(768, 4), 256, 0, stream>>>(
        Wg, 192, 256, 192, 768, WgTh, WgTl, 768L * 192, 256L * 768);

    // st1: PT[t] = NT(WgT_pad[t], x), K=768
    nt_gemm<0, false, false, false, false><<<dim3(32, 2, 4), 256, 0, stream>>>(
        WgTh, WgTl, xh, xl, nullptr, PTh, PTl, nullptr, nullptr, nullptr,
        768, 256, NN, 192, NN, NN, 256L * 768, 0L, 192L * NN, 0);

    // st4: HT[t] = relu(NT(PT[t], G[t]) + bg[t]); G staged from F fp32 (B side)
    nt_gemm<1, true, false, true, false><<<dim3(32, 2, 4), 256, 0, stream>>>(
        PTh, PTl, nullptr, nullptr, F, HTh, HTl, nullptr, bgp, rowss,
        NN, 192, NN, 192, NN, NN, 192L * NN, NPW, 192L * NN, 256);

    // st5 (swapped): combT-tiles = NT(HT, G), stored transposed.
    nt_gemm<0, false, false, true, true><<<dim3(32, 2, 4), 256, 0, stream>>>(
        HTh, HTl, nullptr, nullptr, F, combh, combl, nullptr, nullptr, rowss,
        NN, 192, NN, 192, NN, 768, 192L * NN, NPW, 192L, 0);

    // st6: out = relu(NT(comb, WfT) + bf)
    transpose_split<<<dim3(2304, 1), 256, 0, stream>>>(
        Wf, 768, 768, 768, 768, WfTh, WfTl, 0L, 0L);
    nt_gemm<2, true, true, false, false><<<dim3(12, 16, 1), 256, 0, stream>>>(
        combh, combl, WfTh, WfTl, nullptr, nullptr, nullptr, out, bf, nullptr,
        768, NN, 768, NN, 768, 768, 0L, 0L, 0L, 0);
}